// Round 7
// baseline (213659.473 us; speedup 1.0000x reference)
//
#include <hip/hip_runtime.h>
#include <stdint.h>

// RNN-T greedy decode v9 — exact 1-block-per-CU topology (H-B contention test).
//
// Ledger: v2/v7/v8 (fence+cached, 3-4 rounds, 23-45MB/step) all ~200-211ms ->
// ~40us/step floor INSENSITIVE to round count and traffic bytes. v3-v5
// (all-MALL transport) 344-450ms. v6 (unverified sc0 protocol) FAIL.
// Hypotheses left: H-B (2 blocks/CU contention/skew sets each round's max)
// vs H-A/H-C (fixed per-round fence+atomic-RTT latency).
//
// v9 = v8 with topology-only deltas:
//  * 256 blocks total = 160 GP (v8 gate+pred code verbatim) + 96 OUT x 11
//    cols (clamped-dup cols, v5-verified; covers col 1024 -> blank stage and
//    its extra F2 wait/root add deleted).
//  * Dynamic LDS 82944B (>80KB) forces exactly 1 block/CU; 256 blocks = 256
//    CUs, all co-resident, zero role contention.
//  * Only owner blocks (0..31) wait F3 (v8 made all GP blocks acquire F3).
// Counter tree: F1/F2 10 leaves x16 GP (*10); F3 6 leaves x16 out (*6);
// F4 2 leaves x16 owners (*2). Everything else byte-identical to v8.

typedef unsigned int u32;

constexpr int NGB = 160;              // GP (gate+pred) blocks
constexpr int NOB = 96;               // out blocks (11 cols each, clamped)
constexpr int NBLK = NGB + NOB;       // 256 == #CUs
constexpr int LDSTR = 648;            // padded LDS row stride (2-way alias = free)
constexpr u32 LDS_BYTES = 82944;      // >80KB -> exactly 1 block/CU

// ---- static device scratch ----
__device__ float  g_encT[1000 * 32 * 640];   // enc@Wenc + b_joint, [T][B][J]
__device__ float  g_lut[1025 * 2560];        // embed@Wx + b_lstm (row 1024 = b_lstm)
__device__ float  g_hnew[2 * 32 * 640];      // double-buffered by step parity
__device__ float  g_tnh[32 * 640];           // tanh(joint pre-act)
__device__ double g_cval[32 * 132];          // candidate values (slots 0..95)
__device__ int    g_cidx[32 * 132];          // candidate indices
__device__ int    g_last[32];
__device__ int    g_emit[32];
__device__ u32    g_cnt[64 * 32];            // counters, 128 B apart

// counter slots (each = 32 u32 = 128 B)
constexpr int F1L = 0,  F1R = 10;  // 10 leaves x16 GP blocks   (target *10)
constexpr int F2L = 11, F2R = 21;  // 10 leaves x16 GP blocks   (target *10)
constexpr int F3L = 22, F3R = 28;  // 6 leaves x16 out blocks   (target *6)
constexpr int F4L = 29, F4R = 31;  // 2 leaves x16 owners       (target *2)

__device__ __forceinline__ float sigmf(float x) { return 1.0f / (1.0f + expf(-x)); }

__device__ __forceinline__ void bump(int leaf, int root, int step) {
  // caller: thread 0 after __syncthreads() (all waves' stores vmcnt-drained)
  __builtin_amdgcn_fence(__ATOMIC_RELEASE, "agent");
  u32 old = __hip_atomic_fetch_add(&g_cnt[leaf * 32], 1u, __ATOMIC_RELAXED, __HIP_MEMORY_SCOPE_AGENT);
  if (old + 1u == (u32)(step + 1) * 16u)
    __hip_atomic_fetch_add(&g_cnt[root * 32], 1u, __ATOMIC_RELAXED, __HIP_MEMORY_SCOPE_AGENT);
}

__device__ __forceinline__ void waitc(int root, u32 target) {
  if (threadIdx.x == 0) {
    while (__hip_atomic_load(&g_cnt[root * 32], __ATOMIC_RELAXED, __HIP_MEMORY_SCOPE_AGENT) < target)
      __builtin_amdgcn_s_sleep(1);
    __builtin_amdgcn_fence(__ATOMIC_ACQUIRE, "agent");  // invalidate stale cache lines
  }
  __syncthreads();
}

// ---------------- precompute: LUT = embed @ Wx + b_lstm (row 1024 = b_lstm) -----------
__global__ __launch_bounds__(256) void k_lut(const float* __restrict__ embed,
                                             const float* __restrict__ Wx,
                                             const float* __restrict__ b_lstm) {
  const int tid = threadIdx.x;
  const int cg = blockIdx.x % 10, rg = blockIdx.x / 10;  // rg 0..128
  const int c = cg * 256 + tid;
  const int r0 = rg * 8;
  double acc[8];
  double bl = (double)b_lstm[c];
#pragma unroll
  for (int i = 0; i < 8; i++) acc[i] = bl;
  for (int e = 0; e < 640; e++) {
    double wx = (double)Wx[(size_t)e * 2560 + c];
#pragma unroll
    for (int i = 0; i < 8; i++) {
      int r = r0 + i;
      if (r < 1024) acc[i] += (double)embed[(size_t)r * 640 + e] * wx;
    }
  }
#pragma unroll
  for (int i = 0; i < 8; i++) {
    int r = r0 + i;
    if (r < 1025) g_lut[(size_t)r * 2560 + c] = (float)acc[i];
  }
  if (blockIdx.x == 0) {  // init sync state every call (graph replay safe)
    for (int i = tid; i < 64 * 32; i += 256) g_cnt[i] = 0u;
    if (tid < 32) { g_last[tid] = 1024; g_emit[tid] = 0; }
  }
}

// ------------- precompute: encT[t][b][j] = sum_d enc[b][d][t]*Wenc[d][j] + b_joint[j] --
__global__ __launch_bounds__(256) void k_encproj(const float* __restrict__ enc,
                                                 const float* __restrict__ Wenc,
                                                 const float* __restrict__ bj) {
  __shared__ __align__(16) float As[16][68];
  __shared__ __align__(16) float Bs[16][68];
  const int tid = threadIdx.x;
  const int jt = blockIdx.x % 10, tt = blockIdx.x / 10;  // 10 j-tiles, 16 t-tiles
  const int b = blockIdx.y;
  const int t0 = tt * 64, j0 = jt * 64;
  const int ty = tid >> 4, tx = tid & 15;
  double acc[4][4] = {};
  const float* Ab = enc + (size_t)b * 640 * 1000;
  for (int d0 = 0; d0 < 640; d0 += 16) {
#pragma unroll
    for (int i = 0; i < 4; i++) {
      int idx = tid + i * 256;
      int d = idx >> 6, t = idx & 63;
      As[d][t] = (t0 + t < 1000) ? Ab[(size_t)(d0 + d) * 1000 + t0 + t] : 0.f;
      Bs[d][t] = Wenc[(size_t)(d0 + d) * 640 + j0 + t];
    }
    __syncthreads();
#pragma unroll
    for (int kk = 0; kk < 16; kk++) {
      float4 av = *(const float4*)&As[kk][ty * 4];
      float4 bv = *(const float4*)&Bs[kk][tx * 4];
      float a[4] = {av.x, av.y, av.z, av.w};
      float bb[4] = {bv.x, bv.y, bv.z, bv.w};
#pragma unroll
      for (int i = 0; i < 4; i++)
#pragma unroll
        for (int j = 0; j < 4; j++) acc[i][j] += (double)a[i] * (double)bb[j];
    }
    __syncthreads();
  }
#pragma unroll
  for (int i = 0; i < 4; i++) {
    int t = t0 + ty * 4 + i;
    if (t < 1000)
#pragma unroll
      for (int j = 0; j < 4; j++)
        g_encT[(size_t)t * 20480 + b * 640 + j0 + tx * 4 + j] =
            (float)(acc[i][j] + (double)bj[j0 + tx * 4 + j]);
  }
}

// ------------------------------- persistent decode ------------------------------------
__global__ __launch_bounds__(256) void k_decode(float* __restrict__ out,
                                                const int* __restrict__ lens,
                                                const float* __restrict__ Wh,
                                                const float* __restrict__ Wpred,
                                                const float* __restrict__ Wout,
                                                const float* __restrict__ b_out) {
  extern __shared__ __align__(16) float wsl[];  // 82944B dynamic (forces 1 block/CU)

  const int tid = threadIdx.x;
  const int bid = blockIdx.x;

  if (bid < NGB) {
    // ============ GP role: gates for 4 units + pred for 4 j-cols (v8 verbatim) =======
    const int b = tid >> 3, c0 = tid & 7;
    const int u0 = bid * 4;                    // unit base == pred col base
    for (int idx = tid; idx < 16 * 640; idx += 256) {
      int ci = idx / 640, k = idx - ci * 640;
      int g = ci >> 2, ul = ci & 3;
      wsl[ci * LDSTR + k] = Wh[(size_t)k * 2560 + g * 640 + u0 + ul];
    }
    for (int idx = tid; idx < 4 * 640; idx += 256) {
      int ci = idx / 640, k = idx - ci * 640;
      wsl[(16 + ci) * LDSTR + k] = Wpred[(size_t)k * 640 + u0 + ci];
    }
    __syncthreads();
    const int g1 = c0 >> 2, ul = c0 & 3;
    const int col1 = g1 * 640 + u0 + ul;
    const int col2 = col1 + 1280;
    const float* w1 = &wsl[c0 * LDSTR];
    const float* w2 = &wsl[(c0 + 8) * LDSTR];
    const int cl = c0 >> 1, half = c0 & 1;
    const int j = u0 + cl;
    const float* wp = &wsl[(16 + cl) * LDSTR + half * 320];

    double G1 = 0.0, G2 = 0.0, ccur = 0.0;  // invariant: G = h_committed @ Wh
    float hcur = 0.f;
    const bool owner = (bid < 32);
    const int len_o = owner ? lens[bid] : 0;
    int alive_o = (owner && 0 < len_o) ? 1 : 0;
    int ti = 0, si = 0;

    for (int step = 0; step < 5000; step++) {
      // --- phase A: gates = G + LUT[last]; pointwise; publish h_new ---
      const int last_b = g_last[b];            // ordered by prev step's F4 acquire
      const float* lrow = g_lut + (size_t)last_b * 2560;
      double gate1 = G1 + (double)lrow[col1];
      double gate2 = G2 + (double)lrow[col2];
      double x1 = __shfl_xor(gate1, 4, 64);    // partner holds (f,o)
      double x2 = __shfl_xor(gate2, 4, 64);
      double cn = 0.0; float hn = 0.f;
      if (c0 < 4) {
        float fi = (float)gate1, fg = (float)gate2, ff = (float)x1, fo = (float)x2;
        cn = (double)sigmf(ff) * ccur + (double)sigmf(fi) * (double)tanhf(fg);
        hn = sigmf(fo) * tanhf((float)cn);
        g_hnew[(step & 1) * 20480 + b * 640 + u0 + c0] = hn;
      }
      __syncthreads();
      if (tid == 0) bump(F1L + (bid >> 4), F1R, step);
      waitc(F1R, (u32)(step + 1) * 10u);

      // --- pred dot: tanhvec col j (split-k x2 over lane pairs) ---
      {
        const float* hb = g_hnew + (step & 1) * 20480 + b * 640 + half * 320;
        double a = 0.0;
        for (int k = 0; k < 320; k += 4) {
          float4 h4 = *(const float4*)(hb + k);
          float4 q = *(const float4*)(wp + k);
          a += (double)h4.x * q.x; a += (double)h4.y * q.y;
          a += (double)h4.z * q.z; a += (double)h4.w * q.w;
        }
        a += __shfl_xor(a, 1, 64);
        if (half == 0) {
          double pre = (double)g_encT[(size_t)ti * 20480 + b * 640 + j] + a;
          g_tnh[b * 640 + j] = tanhf((float)pre);
        }
      }
      __syncthreads();
      if (tid == 0) bump(F2L + (bid >> 4), F2R, step);

      // --- phase B: speculative G_spec = h_new @ Wh (overlaps out round) ---
      const float* hb = g_hnew + (step & 1) * 20480 + b * 640;
      double a1 = 0.0, a2 = 0.0;
      for (int k = 0; k < 640; k += 4) {
        float4 h4 = *(const float4*)(hb + k);
        float4 q1 = *(const float4*)(w1 + k);
        float4 q2 = *(const float4*)(w2 + k);
        a1 += (double)h4.x * q1.x; a1 += (double)h4.y * q1.y;
        a1 += (double)h4.z * q1.z; a1 += (double)h4.w * q1.w;
        a2 += (double)h4.x * q2.x; a2 += (double)h4.y * q2.y;
        a2 += (double)h4.z * q2.z; a2 += (double)h4.w * q2.w;
      }

      // --- owners: reduce 96 candidates for their row; publish last/emit ---
      if (owner) {
        waitc(F3R, (u32)(step + 1) * 6u);
        if (tid < 64) {
          double bv = g_cval[bid * 132 + tid]; int bi = g_cidx[bid * 132 + tid];
          if (tid < 32) {
            double v1 = g_cval[bid * 132 + tid + 64]; int i1 = g_cidx[bid * 132 + tid + 64];
            if (v1 > bv || (v1 == bv && i1 < bi)) { bv = v1; bi = i1; }
          }
#pragma unroll
          for (int m = 1; m < 64; m <<= 1) {
            double vv = __shfl_xor(bv, m, 64);
            int ii = __shfl_xor(bi, m, 64);
            if (vv > bv || (vv == bv && ii < bi)) { bv = vv; bi = ii; }
          }
          if (tid == 0) {
            int sym = bi;
            int em = (alive_o && sym != 1024) ? 1 : 0;
            out[(size_t)bid * 5000 + step] = (float)(em ? sym : 1024);
            g_emit[bid] = em;
            if (em) g_last[bid] = sym;
            alive_o = (si == 4) ? ((ti + 1 < len_o) ? 1 : 0) : em;
          }
        }
        __syncthreads();  // owner stores drained before release in bump
        if (tid == 0) bump(F4L + (bid >> 4), F4R, step);
      }
      // --- commit on emit ---
      waitc(F4R, (u32)(step + 1) * 2u);
      if (g_emit[b]) {
        G1 = a1; G2 = a2;
        if (c0 < 4) { ccur = cn; hcur = hn; }
      }
      si++; if (si == 5) { si = 0; ti++; }
    }
    if (c0 < 4) {  // cache_rnn_state = stack([h, c])
      out[160000 + b * 640 + u0 + c0] = hcur;
      out[160000 + 20480 + b * 640 + u0 + c0] = (float)ccur;
    }

  } else {
    // ============ OUT role: 11 Wout cols each (clamped dups; covers blank) =========
    const int o = bid - NGB;         // 0..95
    const int b = tid >> 3, c0 = tid & 7;
    int col0 = o * 11 + c0;          if (col0 > 1024) col0 = 1024;
    const int c1i = (c0 < 3) ? 8 + c0 : c0;
    int col1 = o * 11 + c1i;         if (col1 > 1024) col1 = 1024;
    for (int idx = tid; idx < 11 * 640; idx += 256) {
      int ci = idx / 640, k = idx - ci * 640;
      int gc = o * 11 + ci; if (gc > 1024) gc = 1024;
      wsl[ci * LDSTR + k] = Wout[(size_t)k * 1025 + gc];
    }
    __syncthreads();
    const double bo0 = (double)b_out[col0];
    const double bo1 = (double)b_out[col1];
    const float* wv0 = &wsl[c0 * LDSTR];
    const float* wv1 = &wsl[c1i * LDSTR];

    for (int step = 0; step < 5000; step++) {
      waitc(F2R, (u32)(step + 1) * 10u);
      const float* tb = g_tnh + b * 640;
      double a0 = bo0, a1 = bo1;
      for (int k = 0; k < 640; k += 4) {
        float4 t4 = *(const float4*)(tb + k);
        float4 q0 = *(const float4*)(wv0 + k);
        float4 q1 = *(const float4*)(wv1 + k);
        a0 += (double)t4.x * q0.x; a0 += (double)t4.y * q0.y;
        a0 += (double)t4.z * q0.z; a0 += (double)t4.w * q0.w;
        a1 += (double)t4.x * q1.x; a1 += (double)t4.y * q1.y;
        a1 += (double)t4.z * q1.z; a1 += (double)t4.w * q1.w;
      }
      double bv = a0; int bi = col0;
      if (a1 > bv || (a1 == bv && col1 < bi)) { bv = a1; bi = col1; }
#pragma unroll
      for (int m = 1; m < 8; m <<= 1) {  // argmax over this block's 11 cols
        double v2 = __shfl_xor(bv, m, 64);
        int i2 = __shfl_xor(bi, m, 64);
        if (v2 > bv || (v2 == bv && i2 < bi)) { bv = v2; bi = i2; }
      }
      if (c0 == 0) { g_cval[b * 132 + o] = bv; g_cidx[b * 132 + o] = bi; }
      __syncthreads();
      if (tid == 0) bump(F3L + (o >> 4), F3R, step);
    }
  }
}

extern "C" void kernel_launch(void* const* d_in, const int* in_sizes, int n_in,
                              void* d_out, int out_size, void* d_ws, size_t ws_size,
                              hipStream_t stream) {
  const float* enc = (const float*)d_in[0];
  const int* lens = (const int*)d_in[1];
  const float* embed = (const float*)d_in[2];
  const float* Wx = (const float*)d_in[3];
  const float* Wh = (const float*)d_in[4];
  const float* b_lstm = (const float*)d_in[5];
  const float* Wenc = (const float*)d_in[6];
  const float* Wpred = (const float*)d_in[7];
  const float* b_joint = (const float*)d_in[8];
  const float* Wout = (const float*)d_in[9];
  const float* b_out = (const float*)d_in[10];
  float* out = (float*)d_out;
  (void)d_ws; (void)ws_size; (void)in_sizes; (void)n_in; (void)out_size;

  static bool attr_done = false;  // host-side, not a stream op (graph-capture safe)
  if (!attr_done) {
    hipFuncSetAttribute((const void*)k_decode,
                        hipFuncAttributeMaxDynamicSharedMemorySize, (int)LDS_BYTES);
    attr_done = true;
  }

  hipLaunchKernelGGL(k_lut, dim3(1290), dim3(256), 0, stream, embed, Wx, b_lstm);
  hipLaunchKernelGGL(k_encproj, dim3(160, 32), dim3(256), 0, stream, enc, Wenc, b_joint);
  hipLaunchKernelGGL(k_decode, dim3(NBLK), dim3(256), LDS_BYTES, stream,
                     out, lens, Wh, Wpred, Wout, b_out);
}

// Round 8
// 159692.566 us; speedup vs baseline: 1.3379x; 1.3379x over previous
//
#include <hip/hip_runtime.h>
#include <stdint.h>

// RNN-T greedy decode v10 — v8 topology + hybrid transport (minimal fences).
//
// Ledger: v2/v7/v8 (fence+cached) 200-211ms regardless of round count (3 vs 4),
// MALL bytes (23-45MB/step), or topology (v9 1-block/CU: 213ms). v3-v5
// (all-uncached) 344-450ms. FETCH=920KB/step -> refill BW is not the floor.
// Last live hypothesis: per-block L2-wide cache ops (release wbl2 + acquire inv)
// serialize at the L2 controller; v8 issues ~900/step, invariant to all knobs
// tried so far.
//
// v10 = v8 with transport-only deltas (every primitive session-verified):
//  * h / tanh: ATOMIC stores (MALL-direct, v3-verified) -> NO release fences
//    anywhere; cached reads behind acquire (v2-verified) kept at F1 (GP) and
//    F2 (out) only.
//  * cands (F3) and emit/last (F4): atomic stores AND atomic loads end-to-end
//    (v5-verified) -> no release, no acquire on these edges.
//  * Only owners wait F3 (v9 fix). GP's F4 wait is fence-free.
//  * L2-wide ops/step: ~900 -> 288.
// Ordering: data stores are MALL-visible when each wave's vmcnt drains at
// __syncthreads, before tid0's counter add (v3-v5 reasoning, passed 3x).
// WAR chains: parity-p h overwrite at s+2 gated by F4R(s+1) <= F3R(s+1) <=
// F2R(s+1) <= every GP past spec(s); tanh(s+1) gated by F1R(s+1) <= F4R(s) <=
// F3R(s) <= out done reading tanh(s); cand(s+1) gated by F2R(s+1) <= F4R(s)
// fired <= owners done reading cand(s); emit(s+1) gated by F3R(s+1) <=
// F2R(s+1) <= all GP past phase A(s+1) and commit(s).

typedef unsigned int u32;
typedef unsigned long long u64;

constexpr int NGB = 160;              // GP (gate+pred) blocks
constexpr int NOB = 129;              // out blocks (128 x 8 cols + blank block)
constexpr int NBLK = NGB + NOB;       // 289
constexpr int LDSTR = 648;            // padded LDS row stride (2-way alias = free)

// ---- static device scratch ----
__device__ float  g_encT[1000 * 32 * 640];   // enc@Wenc + b_joint, [T][B][J]
__device__ float  g_lut[1025 * 2560];        // embed@Wx + b_lstm (row 1024 = b_lstm)
__device__ float  g_hnew[2 * 32 * 640];      // double-buffered by step parity
__device__ float  g_tnh[32 * 640];           // tanh(joint pre-act)
__device__ double g_cval[32 * 132];          // candidate values (slots 0..128)
__device__ int    g_cidx[32 * 132];          // candidate indices
__device__ int    g_last[32];
__device__ int    g_emit[32];
__device__ u32    g_cnt[64 * 32];            // counters, 128 B apart

// counter slots (each = 32 u32 = 128 B)
constexpr int F1L = 0,  F1R = 10;  // 10 leaves x16 GP blocks   (target *10)
constexpr int F2L = 11, F2R = 21;  // 10 leaves x16 GP blocks   (target *10)
constexpr int F3L = 22, F3R = 30;  // 8 leaves x16 out + 1 direct (target *9)
constexpr int F4L = 31, F4R = 33;  // 2 leaves x16 owners       (target *2)

__device__ __forceinline__ float sigmf(float x) { return 1.0f / (1.0f + expf(-x)); }

__device__ __forceinline__ void ast_f(float* p, float v) {
  __hip_atomic_store(p, v, __ATOMIC_RELAXED, __HIP_MEMORY_SCOPE_AGENT);
}
__device__ __forceinline__ void ast_i(int* p, int v) {
  __hip_atomic_store(p, v, __ATOMIC_RELAXED, __HIP_MEMORY_SCOPE_AGENT);
}
__device__ __forceinline__ void ast_d(double* p, double v) {
  __hip_atomic_store((u64*)p, (u64)__double_as_longlong(v),
                     __ATOMIC_RELAXED, __HIP_MEMORY_SCOPE_AGENT);
}
__device__ __forceinline__ int ald_i(const int* p) {
  return __hip_atomic_load(p, __ATOMIC_RELAXED, __HIP_MEMORY_SCOPE_AGENT);
}
__device__ __forceinline__ double ald_d(const double* p) {
  u64 v = __hip_atomic_load((const u64*)p, __ATOMIC_RELAXED, __HIP_MEMORY_SCOPE_AGENT);
  return __longlong_as_double((long long)v);
}

// NO release fence: data stores are agent-atomics already MALL-visible after
// each wave's vmcnt drained at the preceding __syncthreads (v3-v5 verified).
__device__ __forceinline__ void bump(int leaf, int root, int step) {
  u32 old = __hip_atomic_fetch_add(&g_cnt[leaf * 32], 1u, __ATOMIC_RELAXED, __HIP_MEMORY_SCOPE_AGENT);
  if (old + 1u == (u32)(step + 1) * 16u)
    __hip_atomic_fetch_add(&g_cnt[root * 32], 1u, __ATOMIC_RELAXED, __HIP_MEMORY_SCOPE_AGENT);
}

// acquire variant: for rounds whose consumers use CACHED bulk reads (F1, F2)
__device__ __forceinline__ void waitc_acq(int root, u32 target) {
  if (threadIdx.x == 0) {
    while (__hip_atomic_load(&g_cnt[root * 32], __ATOMIC_RELAXED, __HIP_MEMORY_SCOPE_AGENT) < target)
      __builtin_amdgcn_s_sleep(1);
    __builtin_amdgcn_fence(__ATOMIC_ACQUIRE, "agent");  // invalidate stale cache lines
  }
  __syncthreads();
}
// fence-free variant: for rounds whose consumers use atomic loads (F3, F4)
__device__ __forceinline__ void waitc_nf(int root, u32 target) {
  if (threadIdx.x == 0) {
    while (__hip_atomic_load(&g_cnt[root * 32], __ATOMIC_RELAXED, __HIP_MEMORY_SCOPE_AGENT) < target)
      __builtin_amdgcn_s_sleep(1);
  }
  __syncthreads();
}

// ---------------- precompute: LUT = embed @ Wx + b_lstm (row 1024 = b_lstm) -----------
__global__ __launch_bounds__(256) void k_lut(const float* __restrict__ embed,
                                             const float* __restrict__ Wx,
                                             const float* __restrict__ b_lstm) {
  const int tid = threadIdx.x;
  const int cg = blockIdx.x % 10, rg = blockIdx.x / 10;  // rg 0..128
  const int c = cg * 256 + tid;
  const int r0 = rg * 8;
  double acc[8];
  double bl = (double)b_lstm[c];
#pragma unroll
  for (int i = 0; i < 8; i++) acc[i] = bl;
  for (int e = 0; e < 640; e++) {
    double wx = (double)Wx[(size_t)e * 2560 + c];
#pragma unroll
    for (int i = 0; i < 8; i++) {
      int r = r0 + i;
      if (r < 1024) acc[i] += (double)embed[(size_t)r * 640 + e] * wx;
    }
  }
#pragma unroll
  for (int i = 0; i < 8; i++) {
    int r = r0 + i;
    if (r < 1025) g_lut[(size_t)r * 2560 + c] = (float)acc[i];
  }
  if (blockIdx.x == 0) {  // init sync state every call (kernel-boundary flush
    for (int i = tid; i < 64 * 32; i += 256) g_cnt[i] = 0u;   // makes these
    if (tid < 32) { g_last[tid] = 1024; g_emit[tid] = 0; }    // device-visible)
  }
}

// ------------- precompute: encT[t][b][j] = sum_d enc[b][d][t]*Wenc[d][j] + b_joint[j] --
__global__ __launch_bounds__(256) void k_encproj(const float* __restrict__ enc,
                                                 const float* __restrict__ Wenc,
                                                 const float* __restrict__ bj) {
  __shared__ __align__(16) float As[16][68];
  __shared__ __align__(16) float Bs[16][68];
  const int tid = threadIdx.x;
  const int jt = blockIdx.x % 10, tt = blockIdx.x / 10;  // 10 j-tiles, 16 t-tiles
  const int b = blockIdx.y;
  const int t0 = tt * 64, j0 = jt * 64;
  const int ty = tid >> 4, tx = tid & 15;
  double acc[4][4] = {};
  const float* Ab = enc + (size_t)b * 640 * 1000;
  for (int d0 = 0; d0 < 640; d0 += 16) {
#pragma unroll
    for (int i = 0; i < 4; i++) {
      int idx = tid + i * 256;
      int d = idx >> 6, t = idx & 63;
      As[d][t] = (t0 + t < 1000) ? Ab[(size_t)(d0 + d) * 1000 + t0 + t] : 0.f;
      Bs[d][t] = Wenc[(size_t)(d0 + d) * 640 + j0 + t];
    }
    __syncthreads();
#pragma unroll
    for (int kk = 0; kk < 16; kk++) {
      float4 av = *(const float4*)&As[kk][ty * 4];
      float4 bv = *(const float4*)&Bs[kk][tx * 4];
      float a[4] = {av.x, av.y, av.z, av.w};
      float bb[4] = {bv.x, bv.y, bv.z, bv.w};
#pragma unroll
      for (int i = 0; i < 4; i++)
#pragma unroll
        for (int j = 0; j < 4; j++) acc[i][j] += (double)a[i] * (double)bb[j];
    }
    __syncthreads();
  }
#pragma unroll
  for (int i = 0; i < 4; i++) {
    int t = t0 + ty * 4 + i;
    if (t < 1000)
#pragma unroll
      for (int j = 0; j < 4; j++)
        g_encT[(size_t)t * 20480 + b * 640 + j0 + tx * 4 + j] =
            (float)(acc[i][j] + (double)bj[j0 + tx * 4 + j]);
  }
}

// ------------------------------- persistent decode ------------------------------------
__global__ __launch_bounds__(256, 2) void k_decode(float* __restrict__ out,
                                                   const int* __restrict__ lens,
                                                   const float* __restrict__ Wh,
                                                   const float* __restrict__ Wpred,
                                                   const float* __restrict__ Wout,
                                                   const float* __restrict__ b_out) {
  __shared__ __align__(16) float wsl[20 * LDSTR];  // GP: 16 Wh cols + 4 Wpred cols

  const int tid = threadIdx.x;
  const int bid = blockIdx.x;

  if (bid < NGB) {
    // ============ GP role: gates for 4 units + pred for 4 j-cols ============
    const int b = tid >> 3, c0 = tid & 7;
    const int u0 = bid * 4;                    // unit base == pred col base
    for (int idx = tid; idx < 16 * 640; idx += 256) {
      int ci = idx / 640, k = idx - ci * 640;
      int g = ci >> 2, ul = ci & 3;
      wsl[ci * LDSTR + k] = Wh[(size_t)k * 2560 + g * 640 + u0 + ul];
    }
    for (int idx = tid; idx < 4 * 640; idx += 256) {
      int ci = idx / 640, k = idx - ci * 640;
      wsl[(16 + ci) * LDSTR + k] = Wpred[(size_t)k * 640 + u0 + ci];
    }
    __syncthreads();
    const int g1 = c0 >> 2, ul = c0 & 3;
    const int col1 = g1 * 640 + u0 + ul;
    const int col2 = col1 + 1280;
    const float* w1 = &wsl[c0 * LDSTR];
    const float* w2 = &wsl[(c0 + 8) * LDSTR];
    const int cl = c0 >> 1, half = c0 & 1;
    const int j = u0 + cl;
    const float* wp = &wsl[(16 + cl) * LDSTR + half * 320];

    double G1 = 0.0, G2 = 0.0, ccur = 0.0;  // invariant: G = h_committed @ Wh
    float hcur = 0.f;
    const bool owner = (bid < 32);
    const int len_o = owner ? lens[bid] : 0;
    int alive_o = (owner && 0 < len_o) ? 1 : 0;
    int ti = 0, si = 0;

    for (int step = 0; step < 5000; step++) {
      // --- phase A: gates = G + LUT[last]; pointwise; publish h_new (atomic) ---
      const int last_b = ald_i(&g_last[b]);    // atomic edge (no fence needed)
      const float* lrow = g_lut + (size_t)last_b * 2560;
      double gate1 = G1 + (double)lrow[col1];
      double gate2 = G2 + (double)lrow[col2];
      double x1 = __shfl_xor(gate1, 4, 64);    // partner holds (f,o)
      double x2 = __shfl_xor(gate2, 4, 64);
      double cn = 0.0; float hn = 0.f;
      if (c0 < 4) {
        float fi = (float)gate1, fg = (float)gate2, ff = (float)x1, fo = (float)x2;
        cn = (double)sigmf(ff) * ccur + (double)sigmf(fi) * (double)tanhf(fg);
        hn = sigmf(fo) * tanhf((float)cn);
        ast_f(&g_hnew[(step & 1) * 20480 + b * 640 + u0 + c0], hn);
      }
      __syncthreads();  // vmcnt drain: atomic h stores MALL-visible before bump
      if (tid == 0) bump(F1L + (bid >> 4), F1R, step);
      waitc_acq(F1R, (u32)(step + 1) * 10u);   // cached h reads below

      // --- pred dot: tanhvec col j (split-k x2 over lane pairs) ---
      {
        const float* hb = g_hnew + (step & 1) * 20480 + b * 640 + half * 320;
        double a = 0.0;
        for (int k = 0; k < 320; k += 4) {
          float4 h4 = *(const float4*)(hb + k);
          float4 q = *(const float4*)(wp + k);
          a += (double)h4.x * q.x; a += (double)h4.y * q.y;
          a += (double)h4.z * q.z; a += (double)h4.w * q.w;
        }
        a += __shfl_xor(a, 1, 64);
        if (half == 0) {
          double pre = (double)g_encT[(size_t)ti * 20480 + b * 640 + j] + a;
          ast_f(&g_tnh[b * 640 + j], tanhf((float)pre));
        }
      }
      __syncthreads();  // vmcnt drain: atomic tanh stores visible before bump
      if (tid == 0) bump(F2L + (bid >> 4), F2R, step);

      // --- phase B: speculative G_spec = h_new @ Wh (overlaps out round) ---
      const float* hb = g_hnew + (step & 1) * 20480 + b * 640;
      double a1 = 0.0, a2 = 0.0;
      for (int k = 0; k < 640; k += 4) {
        float4 h4 = *(const float4*)(hb + k);
        float4 q1 = *(const float4*)(w1 + k);
        float4 q2 = *(const float4*)(w2 + k);
        a1 += (double)h4.x * q1.x; a1 += (double)h4.y * q1.y;
        a1 += (double)h4.z * q1.z; a1 += (double)h4.w * q1.w;
        a2 += (double)h4.x * q2.x; a2 += (double)h4.y * q2.y;
        a2 += (double)h4.z * q2.z; a2 += (double)h4.w * q2.w;
      }

      // --- owners: reduce 129 candidates (atomic loads, fence-free round) ---
      if (owner) {
        waitc_nf(F3R, (u32)(step + 1) * 9u);
        if (tid < 64) {
          double bv = ald_d(&g_cval[bid * 132 + tid]);
          int bi = ald_i(&g_cidx[bid * 132 + tid]);
          double v1 = ald_d(&g_cval[bid * 132 + tid + 64]);
          int i1 = ald_i(&g_cidx[bid * 132 + tid + 64]);
          if (v1 > bv || (v1 == bv && i1 < bi)) { bv = v1; bi = i1; }
          if (tid == 0) {
            double v2 = ald_d(&g_cval[bid * 132 + 128]);
            int i2 = ald_i(&g_cidx[bid * 132 + 128]);
            if (v2 > bv || (v2 == bv && i2 < bi)) { bv = v2; bi = i2; }
          }
#pragma unroll
          for (int m = 1; m < 64; m <<= 1) {
            double vv = __shfl_xor(bv, m, 64);
            int ii = __shfl_xor(bi, m, 64);
            if (vv > bv || (vv == bv && ii < bi)) { bv = vv; bi = ii; }
          }
          if (tid == 0) {
            int sym = bi;
            int em = (alive_o && sym != 1024) ? 1 : 0;
            out[(size_t)bid * 5000 + step] = (float)(em ? sym : 1024);
            ast_i(&g_emit[bid], em);
            if (em) ast_i(&g_last[bid], sym);
            alive_o = (si == 4) ? ((ti + 1 < len_o) ? 1 : 0) : em;
          }
        }
        __syncthreads();  // owner atomic stores drained before bump
        if (tid == 0) bump(F4L + (bid >> 4), F4R, step);
      }
      // --- commit on emit (atomic edge, fence-free round) ---
      waitc_nf(F4R, (u32)(step + 1) * 2u);
      if (ald_i(&g_emit[b])) {
        G1 = a1; G2 = a2;
        if (c0 < 4) { ccur = cn; hcur = hn; }
      }
      si++; if (si == 5) { si = 0; ti++; }
    }
    if (c0 < 4) {  // cache_rnn_state = stack([h, c])
      out[160000 + b * 640 + u0 + c0] = hcur;
      out[160000 + 20480 + b * 640 + u0 + c0] = (float)ccur;
    }

  } else {
    // ============ OUT role: 8 Wout cols each; block 128 = blank col ============
    const int o = bid - NGB;         // 0..128
    const int b = tid >> 3, c = tid & 7;
    const int gcol = o * 8 + c;
    const bool valid = (gcol <= 1024);
    const int col = valid ? gcol : 1024;
    for (int idx = tid; idx < 8 * 640; idx += 256) {
      int ci = idx / 640, k = idx - ci * 640;
      int gc = o * 8 + ci;
      wsl[ci * LDSTR + k] = (gc <= 1024) ? Wout[(size_t)k * 1025 + gc] : 0.f;
    }
    __syncthreads();
    const double bo = (double)b_out[col];
    const float* wv = &wsl[c * LDSTR];

    for (int step = 0; step < 5000; step++) {
      waitc_acq(F2R, (u32)(step + 1) * 10u);   // cached tanh reads below
      const float* tb = g_tnh + b * 640;
      double a = bo;
      for (int k = 0; k < 640; k += 4) {
        float4 t4 = *(const float4*)(tb + k);
        float4 q = *(const float4*)(wv + k);
        a += (double)t4.x * q.x; a += (double)t4.y * q.y;
        a += (double)t4.z * q.z; a += (double)t4.w * q.w;
      }
      double bv = valid ? a : -1.0e300;
      int bi = valid ? col : 0x7fffffff;
#pragma unroll
      for (int m = 1; m < 8; m <<= 1) {  // argmax over this block's 8 cols
        double v2 = __shfl_xor(bv, m, 64);
        int i2 = __shfl_xor(bi, m, 64);
        if (v2 > bv || (v2 == bv && i2 < bi)) { bv = v2; bi = i2; }
      }
      if (c == 0) { ast_d(&g_cval[b * 132 + o], bv); ast_i(&g_cidx[b * 132 + o], bi); }
      __syncthreads();  // atomic cand stores drained before bump
      if (tid == 0) {
        if (o < 128) {
          bump(F3L + (o >> 4), F3R, step);
        } else {  // single blank block: direct root add (no fence needed)
          __hip_atomic_fetch_add(&g_cnt[F3R * 32], 1u, __ATOMIC_RELAXED, __HIP_MEMORY_SCOPE_AGENT);
        }
      }
    }
  }
}

extern "C" void kernel_launch(void* const* d_in, const int* in_sizes, int n_in,
                              void* d_out, int out_size, void* d_ws, size_t ws_size,
                              hipStream_t stream) {
  const float* enc = (const float*)d_in[0];
  const int* lens = (const int*)d_in[1];
  const float* embed = (const float*)d_in[2];
  const float* Wx = (const float*)d_in[3];
  const float* Wh = (const float*)d_in[4];
  const float* b_lstm = (const float*)d_in[5];
  const float* Wenc = (const float*)d_in[6];
  const float* Wpred = (const float*)d_in[7];
  const float* b_joint = (const float*)d_in[8];
  const float* Wout = (const float*)d_in[9];
  const float* b_out = (const float*)d_in[10];
  float* out = (float*)d_out;
  (void)d_ws; (void)ws_size; (void)in_sizes; (void)n_in; (void)out_size;

  hipLaunchKernelGGL(k_lut, dim3(1290), dim3(256), 0, stream, embed, Wx, b_lstm);
  hipLaunchKernelGGL(k_encproj, dim3(160, 32), dim3(256), 0, stream, enc, Wenc, b_joint);
  hipLaunchKernelGGL(k_decode, dim3(NBLK), dim3(256), 0, stream,
                     out, lens, Wh, Wpred, Wout, b_out);
}